// Round 8
// baseline (396.412 us; speedup 1.0000x reference)
//
#include <hip/hip_runtime.h>
#include <math.h>

#define IN_DIM 256
#define HID 64
#define NC 32
#define NEG 0.01f
#define INF_NEG -1e30f
#define SXR 68      // row-major X tile stride (words) for gemm2, full K=64
#define SB 36       // row-major X tile stride for gemm1 BK=32
#define MAXNBK 512  // max buckets (N <= 131072 for 17-bit dst packing)
#define SLOT 8256   // per-bucket tmp capacity; 33KB stride breaks L2 set aliasing
#define BCAP 12288  // bucket scatter LDS capacity (entries)
#define BIN_CHUNK 8192

static inline int ceil_div(int a, int b){ return (a + b - 1) / b; }

static __device__ __forceinline__ float lrelu(float x){ return x > 0.f ? x : NEG * x; }

// ---------------- CSR build ----------------

// Phase A: bucket edges by src>>8 into fixed slots tmp[b*SLOT ...], entry = (src&255)<<17 | dst.
// LDS-reorders each 8192-edge chunk bucket-contiguously so global writes are coalesced runs.
__global__ __launch_bounds__(256) void bin_kernel(const int* __restrict__ src,
      const int* __restrict__ dst, int* __restrict__ cursor,
      unsigned int* __restrict__ tmp, int E, int nbk){
  __shared__ unsigned int payload[BIN_CHUNK];
  __shared__ unsigned short bid[BIN_CHUNK];
  __shared__ int cnt[MAXNBK];
  __shared__ int lofs[MAXNBK];
  __shared__ int gbase[MAXNBK];
  __shared__ int s2[256];
  int tid = threadIdx.x;
  int beg = blockIdx.x * BIN_CHUNK;
  int end = min(E, beg + BIN_CHUNK);
  int len = end - beg;

  for (int i = tid; i < MAXNBK; i += 256) cnt[i] = 0;
  __syncthreads();
  for (int e = beg + tid; e < end; e += 256)
    atomicAdd(&cnt[src[e] >> 8], 1);
  __syncthreads();
  int a0 = cnt[2 * tid], a1 = cnt[2 * tid + 1];
  int pair = a0 + a1;
  s2[tid] = pair; __syncthreads();
  int val = pair;
  for (int off = 1; off < 256; off <<= 1){
    int add = (tid >= off) ? s2[tid - off] : 0;
    __syncthreads();
    val += add; s2[tid] = val;
    __syncthreads();
  }
  int ep = val - pair;
  lofs[2 * tid] = ep;
  lofs[2 * tid + 1] = ep + a0;
  __syncthreads();
  for (int i = tid; i < nbk; i += 256){
    int c = cnt[i];
    gbase[i] = (c > 0) ? atomicAdd(&cursor[i], c) : 0;
  }
  __syncthreads();
  for (int i = tid; i < MAXNBK; i += 256) cnt[i] = 0;
  __syncthreads();
  for (int e = beg + tid; e < end; e += 256){
    int s = src[e];
    int b = s >> 8;
    int r = atomicAdd(&cnt[b], 1);
    int pos = lofs[b] + r;
    payload[pos] = ((unsigned)(s & 255) << 17) | (unsigned)dst[e];
    bid[pos] = (unsigned short)b;
  }
  __syncthreads();
  for (int pos = tid; pos < len; pos += 256){
    int b = bid[pos];
    int idx = pos - lofs[b];
    int g = gbase[b] + idx;
    if (g < SLOT) tmp[(size_t)b * SLOT + g] = payload[pos];
  }
}

// Phase B: one block per bucket. Derives its own segment base, derives row_ptr,
// scatters to exact positions in LDS, writes csr coalesced.
__global__ __launch_bounds__(256) void bucket_scatter_kernel(const unsigned int* __restrict__ tmp,
      const int* __restrict__ cursor, int* __restrict__ row_ptr, int* __restrict__ csr,
      int n, int nbk){
  __shared__ int red[256];
  __shared__ int cnt[256];
  __shared__ int cur[256];
  __shared__ int lbuf[BCAP];
  int tid = threadIdx.x;
  int b = blockIdx.x;
  int partial = 0;
  for (int i = tid; i < b; i += 256) partial += min(cursor[i], SLOT);
  red[tid] = partial;
  __syncthreads();
  for (int s = 128; s > 0; s >>= 1){
    if (tid < s) red[tid] += red[tid + s];
    __syncthreads();
  }
  int segb = red[0];
  int n0 = b << 8;
  int nn = min(256, n - n0);
  int len = min(cursor[b], SLOT);
  const unsigned int* T = tmp + (size_t)b * SLOT;
  cnt[tid] = 0;
  __syncthreads();
  for (int e = tid; e < len; e += 256) atomicAdd(&cnt[T[e] >> 17], 1);
  __syncthreads();
  int tv = cnt[tid];
  int val = tv;
  for (int off = 1; off < 256; off <<= 1){
    int add = (tid >= off) ? cnt[tid - off] : 0;
    __syncthreads();
    val += add; cnt[tid] = val;
    __syncthreads();
  }
  int excl = val - tv;
  cur[tid] = excl;
  if (tid < nn) row_ptr[n0 + tid] = segb + excl;
  if (n0 + nn == n && tid == 0) row_ptr[n] = segb + len;
  __syncthreads();
  if (len <= BCAP){
    for (int e = tid; e < len; e += 256){
      unsigned v = T[e];
      int pos = atomicAdd(&cur[v >> 17], 1);
      lbuf[pos] = (int)(v & 0x1FFFF);
    }
    __syncthreads();
    for (int e = tid; e < len; e += 256) csr[segb + e] = lbuf[e];
  } else {
    for (int e = tid; e < len; e += 256){
      unsigned v = T[e];
      int pos = atomicAdd(&cur[v >> 17], 1);
      csr[segb + pos] = (int)(v & 0x1FFFF);
    }
  }
}

// ---- fallback CSR path (N > 2^17 only; never hit at this problem size) ----

__global__ void hist_kernel(const int* __restrict__ src, int* __restrict__ counts, int E){
  int i = blockIdx.x * blockDim.x + threadIdx.x;
  if (i < E) atomicAdd(&counts[src[i]], 1);
}
__global__ void scan_blocks_kernel(const int* __restrict__ counts, int* __restrict__ excl,
                                   int* __restrict__ bsums, int n){
  __shared__ int sh[256];
  int tid = threadIdx.x;
  int base = blockIdx.x * 1024 + tid * 4;
  int c[4]; int tsum = 0;
  #pragma unroll
  for (int j = 0; j < 4; j++){ int i = base + j; c[j] = (i < n) ? counts[i] : 0; tsum += c[j]; }
  sh[tid] = tsum; __syncthreads();
  int val = tsum;
  for (int off = 1; off < 256; off <<= 1){
    int add = (tid >= off) ? sh[tid - off] : 0;
    __syncthreads();
    val += add; sh[tid] = val;
    __syncthreads();
  }
  int p = val - tsum;
  #pragma unroll
  for (int j = 0; j < 4; j++){ int i = base + j; if (i < n) excl[i] = p; p += c[j]; }
  if (tid == 255) bsums[blockIdx.x] = val;
}
__global__ void scan_sums_kernel(int* __restrict__ bsums, int* __restrict__ row_ptr,
                                 int nb, int n, int E){
  __shared__ int sh[256];
  int tid = threadIdx.x;
  int v = (tid < nb) ? bsums[tid] : 0;
  sh[tid] = v; __syncthreads();
  int val = v;
  for (int off = 1; off < 256; off <<= 1){
    int add = (tid >= off) ? sh[tid - off] : 0;
    __syncthreads();
    val += add; sh[tid] = val;
    __syncthreads();
  }
  if (tid < nb) bsums[tid] = val - v;
  if (tid == 0) row_ptr[n] = E;
}
__global__ void add_offsets_kernel(int* __restrict__ excl, const int* __restrict__ bsums, int n){
  int i = blockIdx.x * 1024 + threadIdx.x;
  if (i < n) excl[i] += bsums[blockIdx.x];
}
__global__ void scatter_kernel(const int* __restrict__ src, const int* __restrict__ dst,
                               const int* __restrict__ row_ptr, int* __restrict__ fill,
                               int* __restrict__ csr, int E){
  int i = blockIdx.x * blockDim.x + threadIdx.x;
  if (i >= E) return;
  int s = src[i];
  int pos = row_ptr[s] + atomicAdd(&fill[s], 1);
  csr[pos] = dst[i];
}

// ---------------- GEMM 1: X[N,256] @ W1[256,64] -> H, s, d ----------------
// BM=128, BK=32 (LDS 26.6KB -> 6 blocks/CU), thread owns 8x4, dual register prefetch.

__global__ __launch_bounds__(256) void gemm1_kernel(const float* __restrict__ X, const float* __restrict__ W,
      const float* __restrict__ a, float* __restrict__ H,
      float* __restrict__ svec, float* __restrict__ dvec, int n){
  __shared__ float xs[128 * SB];   // [row][k], 18432 B
  __shared__ float ws[32 * 64];    // [k][col],  8192 B
  int tid = threadIdx.x;
  int r0 = blockIdx.x * 128;
  int tr = tid >> 4;
  int tc = tid & 15;

  float4 pfx[4]; float4 pfw[2];
  #pragma unroll
  for (int p = 0; p < 4; p++){
    int idx = p * 256 + tid;
    int row = idx >> 3, c8 = idx & 7;
    int gr = r0 + row;
    pfx[p] = make_float4(0.f, 0.f, 0.f, 0.f);
    if (gr < n) pfx[p] = *(const float4*)(X + (size_t)gr * IN_DIM + c8 * 4);
  }
  #pragma unroll
  for (int p = 0; p < 2; p++){
    int idx = p * 256 + tid;
    int k = idx >> 4, c4 = idx & 15;
    pfw[p] = *(const float4*)(W + (size_t)k * 64 + c4 * 4);
  }

  float acc[8][4];
  #pragma unroll
  for (int i = 0; i < 8; i++)
    #pragma unroll
    for (int j = 0; j < 4; j++) acc[i][j] = 0.f;

  for (int kb = 0; kb < 8; kb++){
    __syncthreads();
    #pragma unroll
    for (int p = 0; p < 4; p++){
      int idx = p * 256 + tid;
      int row = idx >> 3, c8 = idx & 7;
      *(float4*)(xs + row * SB + c8 * 4) = pfx[p];
    }
    #pragma unroll
    for (int p = 0; p < 2; p++){
      int idx = p * 256 + tid;
      int k = idx >> 4, c4 = idx & 15;
      *(float4*)(ws + k * 64 + c4 * 4) = pfw[p];
    }
    if (kb < 7){
      #pragma unroll
      for (int p = 0; p < 4; p++){
        int idx = p * 256 + tid;
        int row = idx >> 3, c8 = idx & 7;
        int gr = r0 + row;
        pfx[p] = make_float4(0.f, 0.f, 0.f, 0.f);
        if (gr < n) pfx[p] = *(const float4*)(X + (size_t)gr * IN_DIM + (kb + 1) * 32 + c8 * 4);
      }
      #pragma unroll
      for (int p = 0; p < 2; p++){
        int idx = p * 256 + tid;
        int k = idx >> 4, c4 = idx & 15;
        pfw[p] = *(const float4*)(W + (size_t)((kb + 1) * 32 + k) * 64 + c4 * 4);
      }
    }
    __syncthreads();
    for (int kq = 0; kq < 8; kq++){
      float xr[8][4];
      #pragma unroll
      for (int i = 0; i < 8; i++){
        float4 v = *(const float4*)(xs + (tr * 8 + i) * SB + kq * 4);
        xr[i][0] = v.x; xr[i][1] = v.y; xr[i][2] = v.z; xr[i][3] = v.w;
      }
      #pragma unroll
      for (int dk = 0; dk < 4; dk++){
        float4 w4 = *(const float4*)(ws + (size_t)(kq * 4 + dk) * 64 + tc * 4);
        float wv[4] = {w4.x, w4.y, w4.z, w4.w};
        #pragma unroll
        for (int i = 0; i < 8; i++)
          #pragma unroll
          for (int j = 0; j < 4; j++) acc[i][j] = fmaf(xr[i][dk], wv[j], acc[i][j]);
      }
    }
  }

  float av[4], bv[4];
  #pragma unroll
  for (int j = 0; j < 4; j++){ av[j] = a[tc * 4 + j]; bv[j] = a[64 + tc * 4 + j]; }
  float sp[8], dp[8];
  #pragma unroll
  for (int i = 0; i < 8; i++){
    float s = 0.f, d = 0.f;
    #pragma unroll
    for (int j = 0; j < 4; j++){ s = fmaf(acc[i][j], av[j], s); d = fmaf(acc[i][j], bv[j], d); }
    sp[i] = s; dp[i] = d;
  }
  #pragma unroll
  for (int off = 1; off < 16; off <<= 1){
    #pragma unroll
    for (int i = 0; i < 8; i++){
      sp[i] += __shfl_xor(sp[i], off, 16);
      dp[i] += __shfl_xor(dp[i], off, 16);
    }
  }
  #pragma unroll
  for (int i = 0; i < 8; i++){
    int r = r0 + tr * 8 + i;
    if (r < n){
      *(float4*)(H + (size_t)r * 64 + tc * 4) = make_float4(acc[i][0], acc[i][1], acc[i][2], acc[i][3]);
      if (tc == 0){ svec[r] = sp[i]; dvec[r] = dp[i]; }
    }
  }
}

// ---------------- GEMM 2: hid[N,64] @ W2[64,32] -> H2, s, d ----------------

__global__ __launch_bounds__(256) void gemm2_kernel(const float* __restrict__ X, const float* __restrict__ W,
      const float* __restrict__ a, float* __restrict__ H,
      float* __restrict__ svec, float* __restrict__ dvec, int n){
  __shared__ float xs[128 * SXR];
  __shared__ float ws[64 * 32];
  int tid = threadIdx.x;
  int r0 = blockIdx.x * 128;
  int tr = tid >> 4;
  int tc = tid & 15;
  int srow = tid >> 4, sc4 = tid & 15;

  #pragma unroll
  for (int p = 0; p < 8; p++){
    int row = p * 16 + srow;
    int gr = r0 + row;
    float4 v = make_float4(0.f, 0.f, 0.f, 0.f);
    if (gr < n) v = *(const float4*)(X + (size_t)gr * HID + sc4 * 4);
    *(float4*)(xs + row * SXR + sc4 * 4) = v;
  }
  #pragma unroll
  for (int p = 0; p < 2; p++){
    int idx = p * 256 + tid;
    int k = idx >> 3, c4 = idx & 7;
    *(float4*)(ws + k * 32 + c4 * 4) = *(const float4*)(W + (size_t)k * 32 + c4 * 4);
  }
  __syncthreads();

  float acc[8][2];
  #pragma unroll
  for (int i = 0; i < 8; i++){ acc[i][0] = 0.f; acc[i][1] = 0.f; }

  for (int kq = 0; kq < 16; kq++){
    float xr[8][4];
    #pragma unroll
    for (int i = 0; i < 8; i++){
      float4 v = *(const float4*)(xs + (tr * 8 + i) * SXR + kq * 4);
      xr[i][0] = v.x; xr[i][1] = v.y; xr[i][2] = v.z; xr[i][3] = v.w;
    }
    #pragma unroll
    for (int dk = 0; dk < 4; dk++){
      float2 w2 = *(const float2*)(ws + (size_t)(kq * 4 + dk) * 32 + tc * 2);
      #pragma unroll
      for (int i = 0; i < 8; i++){
        acc[i][0] = fmaf(xr[i][dk], w2.x, acc[i][0]);
        acc[i][1] = fmaf(xr[i][dk], w2.y, acc[i][1]);
      }
    }
  }

  float a0 = a[tc * 2], a1 = a[tc * 2 + 1];
  float b0 = a[32 + tc * 2], b1 = a[32 + tc * 2 + 1];
  float sp[8], dp[8];
  #pragma unroll
  for (int i = 0; i < 8; i++){
    sp[i] = fmaf(acc[i][0], a0, acc[i][1] * a1);
    dp[i] = fmaf(acc[i][0], b0, acc[i][1] * b1);
  }
  #pragma unroll
  for (int off = 1; off < 16; off <<= 1){
    #pragma unroll
    for (int i = 0; i < 8; i++){
      sp[i] += __shfl_xor(sp[i], off, 16);
      dp[i] += __shfl_xor(dp[i], off, 16);
    }
  }
  #pragma unroll
  for (int i = 0; i < 8; i++){
    int r = r0 + tr * 8 + i;
    if (r < n){
      *(float2*)(H + (size_t)r * NC + tc * 2) = make_float2(acc[i][0], acc[i][1]);
      if (tc == 0){ svec[r] = sp[i]; dvec[r] = dp[i]; }
    }
  }
}

// ---------------- Aggregate layer 1: one wave per node, D=64 ----------------
// 64 lanes = 4 edge-subgroups x 16 feature-lanes. Gather loop trip count is
// WAVE-UNIFORM (ceil(cnt/4)) so every __shfl executes with all 64 lanes active
// (ds_bpermute from an exec-masked lane returns undefined data — round-7 bug).

__global__ __launch_bounds__(256) void agg1_kernel(const float* __restrict__ H, const float* __restrict__ sv,
      const float* __restrict__ dv, const int* __restrict__ row_ptr, const int* __restrict__ csr,
      float* __restrict__ out, int n){
  int g = (blockIdx.x * 256 + threadIdx.x) >> 6;
  if (g >= n) return;
  int lane = threadIdx.x & 63;
  int sub = lane >> 4, fl = lane & 15;
  int beg = row_ptr[g], end = row_ptr[g + 1];
  float si = sv[g];
  float m = INF_NEG, l = 0.f;
  float ox = 0.f, oy = 0.f, oz = 0.f, ow = 0.f;

  for (int cb = beg; cb < end; cb += 64){
    int cnt = min(64, end - cb);
    int dd = 0; float ev = INF_NEG;
    if (lane < cnt){ dd = csr[cb + lane]; ev = lrelu(si + dv[dd]); }
    float lm = ev;
    #pragma unroll
    for (int off = 1; off < 64; off <<= 1) lm = fmaxf(lm, __shfl_xor(lm, off, 64));
    float nm = fmaxf(m, lm);
    float alpha = __expf(m - nm);
    m = nm;
    float wgt = __expf(ev - nm);   // OOB lanes -> 0
    float ll = wgt;
    #pragma unroll
    for (int off = 1; off < 64; off <<= 1) ll += __shfl_xor(ll, off, 64);
    l = l * alpha + ll;
    ox *= alpha; oy *= alpha; oz *= alpha; ow *= alpha;
    int trips = (cnt + 3) >> 2;      // wave-uniform
    for (int t = 0; t < trips; t++){
      int j = t * 4 + sub;
      int js = min(j, cnt - 1);      // always an active source lane
      float wj = __shfl(wgt, js, 64);
      int dj = __shfl(dd, js, 64);
      if (j < cnt){
        float4 v = *(const float4*)(H + (size_t)dj * 64 + fl * 4);
        ox = fmaf(wj, v.x, ox); oy = fmaf(wj, v.y, oy);
        oz = fmaf(wj, v.z, oz); ow = fmaf(wj, v.w, ow);
      }
    }
  }
  // merge the 4 subgroup partials (all lanes converged here)
  ox += __shfl_xor(ox, 16, 64); ox += __shfl_xor(ox, 32, 64);
  oy += __shfl_xor(oy, 16, 64); oy += __shfl_xor(oy, 32, 64);
  oz += __shfl_xor(oz, 16, 64); oz += __shfl_xor(oz, 32, 64);
  ow += __shfl_xor(ow, 16, 64); ow += __shfl_xor(ow, 32, 64);
  float inv = (l > 0.f) ? 1.f / l : 0.f;
  ox *= inv; oy *= inv; oz *= inv; ow *= inv;
  ox = ox > 0.f ? ox : __expf(ox) - 1.f;
  oy = oy > 0.f ? oy : __expf(oy) - 1.f;
  oz = oz > 0.f ? oz : __expf(oz) - 1.f;
  ow = ow > 0.f ? ow : __expf(ow) - 1.f;
  if (sub == 0)
    *(float4*)(out + (size_t)g * 64 + fl * 4) = make_float4(ox, oy, oz, ow);
}

// ---------------- Aggregate layer 2: one wave per node, D=32, + log_softmax ----------------
// 64 lanes = 8 edge-subgroups x 8 feature-lanes. Same uniform-trip gather.

__global__ __launch_bounds__(256) void agg2_kernel(const float* __restrict__ H, const float* __restrict__ sv,
      const float* __restrict__ dv, const int* __restrict__ row_ptr, const int* __restrict__ csr,
      float* __restrict__ out, int n){
  int g = (blockIdx.x * 256 + threadIdx.x) >> 6;
  if (g >= n) return;
  int lane = threadIdx.x & 63;
  int sub = lane >> 3, fl = lane & 7;
  int beg = row_ptr[g], end = row_ptr[g + 1];
  float si = sv[g];
  float m = INF_NEG, l = 0.f;
  float ox = 0.f, oy = 0.f, oz = 0.f, ow = 0.f;

  for (int cb = beg; cb < end; cb += 64){
    int cnt = min(64, end - cb);
    int dd = 0; float ev = INF_NEG;
    if (lane < cnt){ dd = csr[cb + lane]; ev = lrelu(si + dv[dd]); }
    float lm = ev;
    #pragma unroll
    for (int off = 1; off < 64; off <<= 1) lm = fmaxf(lm, __shfl_xor(lm, off, 64));
    float nm = fmaxf(m, lm);
    float alpha = __expf(m - nm);
    m = nm;
    float wgt = __expf(ev - nm);
    float ll = wgt;
    #pragma unroll
    for (int off = 1; off < 64; off <<= 1) ll += __shfl_xor(ll, off, 64);
    l = l * alpha + ll;
    ox *= alpha; oy *= alpha; oz *= alpha; ow *= alpha;
    int trips = (cnt + 7) >> 3;      // wave-uniform
    for (int t = 0; t < trips; t++){
      int j = t * 8 + sub;
      int js = min(j, cnt - 1);
      float wj = __shfl(wgt, js, 64);
      int dj = __shfl(dd, js, 64);
      if (j < cnt){
        float4 v = *(const float4*)(H + (size_t)dj * 32 + fl * 4);
        ox = fmaf(wj, v.x, ox); oy = fmaf(wj, v.y, oy);
        oz = fmaf(wj, v.z, oz); ow = fmaf(wj, v.w, ow);
      }
    }
  }
  ox += __shfl_xor(ox, 8, 64); ox += __shfl_xor(ox, 16, 64); ox += __shfl_xor(ox, 32, 64);
  oy += __shfl_xor(oy, 8, 64); oy += __shfl_xor(oy, 16, 64); oy += __shfl_xor(oy, 32, 64);
  oz += __shfl_xor(oz, 8, 64); oz += __shfl_xor(oz, 16, 64); oz += __shfl_xor(oz, 32, 64);
  ow += __shfl_xor(ow, 8, 64); ow += __shfl_xor(ow, 16, 64); ow += __shfl_xor(ow, 32, 64);
  float inv = (l > 0.f) ? 1.f / l : 0.f;
  ox *= inv; oy *= inv; oz *= inv; ow *= inv;
  // log_softmax across the 32 classes (8-lane group owns 4 each; all converged)
  float tm = fmaxf(fmaxf(ox, oy), fmaxf(oz, ow));
  #pragma unroll
  for (int off = 1; off < 8; off <<= 1) tm = fmaxf(tm, __shfl_xor(tm, off, 8));
  float se = __expf(ox - tm) + __expf(oy - tm) + __expf(oz - tm) + __expf(ow - tm);
  #pragma unroll
  for (int off = 1; off < 8; off <<= 1) se += __shfl_xor(se, off, 8);
  float lg = tm + __logf(se);
  if (sub == 0)
    *(float4*)(out + (size_t)g * 32 + fl * 4) = make_float4(ox - lg, oy - lg, oz - lg, ow - lg);
}

// ---------------- launch ----------------

extern "C" void kernel_launch(void* const* d_in, const int* in_sizes, int n_in,
                              void* d_out, int out_size, void* d_ws, size_t ws_size,
                              hipStream_t stream) {
  (void)n_in; (void)out_size; (void)ws_size;
  const float* X  = (const float*)d_in[0];
  const int*   EI = (const int*)d_in[1];
  const float* W1 = (const float*)d_in[2];
  const float* W2 = (const float*)d_in[3];
  const float* A1 = (const float*)d_in[4];
  const float* A2 = (const float*)d_in[5];
  float* out = (float*)d_out;

  int N = in_sizes[0] / IN_DIM;
  int E = in_sizes[1] / 2;
  const int* src = EI;
  const int* dst = EI + E;

  auto align_up = [](size_t x){ return (x + 511) & ~(size_t)511; };
  char* w = (char*)d_ws;
  int* counts  = (int*)w;   w += align_up((size_t)N * 4);          // fallback fill only
  int* cursor  = (int*)w;   w += align_up((size_t)MAXNBK * 4);
  int* row_ptr = (int*)w;   w += align_up((size_t)(N + 1) * 4);
  int* bsums   = (int*)w;   w += align_up(1024);
  int* csr     = (int*)w;   w += align_up((size_t)E * 4);
  float* H1    = (float*)w; w += align_up((size_t)N * 64 * 4);
  float* hid   = (float*)w; w += align_up((size_t)N * 64 * 4);
  float* s1    = (float*)w; w += align_up((size_t)N * 4);
  float* d1    = (float*)w; w += align_up((size_t)N * 4);
  float* s2    = (float*)w; w += align_up((size_t)N * 4);
  float* d2    = (float*)w; w += align_up((size_t)N * 4);
  float* H2    = H1;                       // H1 dead after agg1; reuse
  unsigned int* tmp = (unsigned int*)hid;  // hid dead until agg1; nbk*SLOT*4 <= N*64*4

  int nbk = ceil_div(N, 256);

  if (N <= (1 << 17) && nbk <= MAXNBK && (size_t)nbk * SLOT <= (size_t)N * 64){
    hipMemsetAsync(cursor, 0, (size_t)nbk * 4, stream);
    bin_kernel<<<ceil_div(E, BIN_CHUNK), 256, 0, stream>>>(src, dst, cursor, tmp, E, nbk);
    bucket_scatter_kernel<<<nbk, 256, 0, stream>>>(tmp, cursor, row_ptr, csr, N, nbk);
  } else {
    int nb = ceil_div(N, 1024);
    hipMemsetAsync(counts, 0, (size_t)N * 4, stream);
    hist_kernel<<<ceil_div(E, 256), 256, 0, stream>>>(src, counts, E);
    scan_blocks_kernel<<<nb, 256, 0, stream>>>(counts, row_ptr, bsums, N);
    scan_sums_kernel<<<1, 256, 0, stream>>>(bsums, row_ptr, nb, N, E);
    add_offsets_kernel<<<nb, 1024, 0, stream>>>(row_ptr, bsums, N);
    hipMemsetAsync(counts, 0, (size_t)N * 4, stream);
    scatter_kernel<<<ceil_div(E, 256), 256, 0, stream>>>(src, dst, row_ptr, counts, csr, E);
  }

  gemm1_kernel<<<ceil_div(N, 128), 256, 0, stream>>>(X, W1, A1, H1, s1, d1, N);
  agg1_kernel<<<ceil_div(N, 4), 256, 0, stream>>>(H1, s1, d1, row_ptr, csr, hid, N);
  gemm2_kernel<<<ceil_div(N, 128), 256, 0, stream>>>(hid, W2, A2, H2, s2, d2, N);
  agg2_kernel<<<ceil_div(N, 4), 256, 0, stream>>>(H2, s2, d2, row_ptr, csr, out, N);
}